// Round 1
// baseline (254.622 us; speedup 1.0000x reference)
//
#include <hip/hip_runtime.h>
#include <math.h>

// AdderNet 3x3 "convolution" + residual + sign(y)*|y|^alpha, fp32.
// B=8, C=O=64, H=W=64, K=3, pad=1.
// out[b,o,i,j] = x[b,o,i,j] - sum_{c,kh,kw} |x[b,c,i+kh-1,j+kw-1] - w[o,c,kh,kw]|
// then r = sign(y)*|y|^alpha.

#define B_ 8
#define C_ 64
#define H_ 64
#define W_ 64
#define O_ 64
#define CC 8   // c-chunk staged in LDS per iteration

// One-time weight transpose: w[o][c][tap] -> wT[c][tap][o]
// so main-kernel staging is a contiguous coalesced copy and LDS reads over o
// are aligned float4.
__global__ void wtrans_kernel(const float* __restrict__ w, float* __restrict__ wT) {
    int e = blockIdx.x * 256 + threadIdx.x;
    if (e < C_ * 9 * O_) {
        int c   = e / (9 * O_);
        int rem = e % (9 * O_);
        int tap = rem / O_;
        int o   = rem % O_;
        wT[e] = w[(o * C_ + c) * 9 + tap];
    }
}

// Block: 128 threads = 16 j-segments x 8 o-groups. Covers (b, row i0), all
// 64 j, all 64 o. Thread tile: 4 consecutive j x 8 o = 32 accumulators.
__global__ __launch_bounds__(128) void adder_kernel(
        const float* __restrict__ x,
        const float* __restrict__ wT,
        const float* __restrict__ alpha_p,
        float* __restrict__ out) {
    const int i0  = blockIdx.x;       // output row
    const int b   = blockIdx.y;
    const int tid = threadIdx.x;
    const int jseg = tid & 15;        // 16 segments of 4 cols
    const int o0   = (tid >> 4) * 8;  // 8 o-groups of 8
    const int j0   = jseg * 4;

    __shared__ float s_w[CC * 9 * 64];   // [cc][tap][o], o contiguous
    __shared__ float s_x[CC * 3 * 66];   // [cc][r][col], col = j_global+1 (halo)

    float acc[8][4];
    #pragma unroll
    for (int oo = 0; oo < 8; ++oo)
        #pragma unroll
        for (int j = 0; j < 4; ++j) acc[oo][j] = 0.f;

    for (int c0 = 0; c0 < C_; c0 += CC) {
        __syncthreads();
        // Stage weights: contiguous 4608 floats = 1152 float4, coalesced.
        {
            const float4* __restrict__ wsrc = (const float4*)(wT + c0 * 576);
            float4* wdst = (float4*)s_w;
            #pragma unroll
            for (int k = 0; k < 9; ++k)
                wdst[tid + k * 128] = wsrc[tid + k * 128];
        }
        // Stage x rows i0-1..i0+1 for CC channels, cols -1..64 (zero halo).
        for (int e = tid; e < CC * 3 * 66; e += 128) {
            int cc  = e / 198;
            int rem = e % 198;
            int r   = rem / 66;
            int col = rem % 66;
            int ir  = i0 - 1 + r;
            int jc  = col - 1;
            float v = 0.f;
            if ((unsigned)ir < 64u && (unsigned)jc < 64u)
                v = x[((b * C_ + c0 + cc) * H_ + ir) * W_ + jc];
            s_x[e] = v;
        }
        __syncthreads();

        for (int cc = 0; cc < CC; ++cc) {
            // 6 x-values per row cover j0..j0+3 for kw=0..2.
            float xv[3][6];
            #pragma unroll
            for (int r = 0; r < 3; ++r)
                #pragma unroll
                for (int t = 0; t < 6; ++t)
                    xv[r][t] = s_x[cc * 198 + r * 66 + j0 + t];

            #pragma unroll
            for (int kh = 0; kh < 3; ++kh) {
                #pragma unroll
                for (int kw = 0; kw < 3; ++kw) {
                    const float* wp = &s_w[(cc * 9 + kh * 3 + kw) * 64 + o0];
                    float wv[8];
                    *(float4*)&wv[0] = *(const float4*)&wp[0];
                    *(float4*)&wv[4] = *(const float4*)&wp[4];
                    #pragma unroll
                    for (int oo = 0; oo < 8; ++oo)
                        #pragma unroll
                        for (int j = 0; j < 4; ++j)
                            acc[oo][j] += fabsf(xv[kh][j + kw] - wv[oo]);
                }
            }
        }
    }

    const float alpha = alpha_p[0];
    #pragma unroll
    for (int oo = 0; oo < 8; ++oo) {
        const int o = o0 + oo;
        const float4 xr = *(const float4*)&x[((b * C_ + o) * H_ + i0) * W_ + j0];
        float y0 = xr.x - acc[oo][0];
        float y1 = xr.y - acc[oo][1];
        float y2 = xr.z - acc[oo][2];
        float y3 = xr.w - acc[oo][3];
        float4 res;
        res.x = copysignf(powf(fabsf(y0), alpha), y0);
        res.y = copysignf(powf(fabsf(y1), alpha), y1);
        res.z = copysignf(powf(fabsf(y2), alpha), y2);
        res.w = copysignf(powf(fabsf(y3), alpha), y3);
        *(float4*)&out[((b * O_ + o) * H_ + i0) * W_ + j0] = res;
    }
}

extern "C" void kernel_launch(void* const* d_in, const int* in_sizes, int n_in,
                              void* d_out, int out_size, void* d_ws, size_t ws_size,
                              hipStream_t stream) {
    const float* x     = (const float*)d_in[0];
    const float* w     = (const float*)d_in[1];
    const float* alpha = (const float*)d_in[2];
    float* out = (float*)d_out;
    float* wT  = (float*)d_ws;   // 64*9*64 floats = 147456 B

    wtrans_kernel<<<(C_ * 9 * O_ + 255) / 256, 256, 0, stream>>>(w, wT);
    adder_kernel<<<dim3(H_, B_), 128, 0, stream>>>(x, wT, alpha, out);
}

// Round 2
// 152.933 us; speedup vs baseline: 1.6649x; 1.6649x over previous
//
#include <hip/hip_runtime.h>
#include <math.h>

// AdderNet 3x3 "convolution" + residual + sign(y)*|y|^alpha, fp32.
// B=8, C=O=64, H=W=64, K=3, pad=1.
// out[b,o,i,j] = x[b,o,i,j] - sum_{c,kh,kw} |xpad[b,c,i+kh-1,j+kw-1] - w[o,c,kh,kw]|
// then r = sign(y)*|y|^alpha.   NOTE: zero-pad taps contribute |0 - w|.
//
// Design: lane = column j (wave64 == W). One wave per (b, i, o-group-of-8).
//   - x: 3 coalesced b32 global loads per channel (L1/L2-resident),
//     software-pipelined one channel ahead. j+-1 neighbors via DPP
//     wave_shr:1 / wave_shl:1 with bound_ctrl zero-fill == the zero halo.
//   - w: wave-uniform -> scalar loads into SGPRs (pre-transposed so each
//     (c, o-group) slice is 72 contiguous 16B-aligned floats). No LDS at all.
//   - 4096 waves = 4 waves/SIMD; abs-op = v_sub + v_add(|mod|) = 2 instr.

#define DPP_WAVE_SHL1 0x130
#define DPP_WAVE_SHR1 0x138

__device__ __forceinline__ float dpp_left(float v) {
    // lane n <- lane n-1 (x[j-1]); lane 0 <- 0 (left zero halo)
    int r = __builtin_amdgcn_update_dpp(0, __float_as_int(v),
                                        DPP_WAVE_SHR1, 0xF, 0xF, true);
    return __int_as_float(r);
}
__device__ __forceinline__ float dpp_right(float v) {
    // lane n <- lane n+1 (x[j+1]); lane 63 <- 0 (right zero halo)
    int r = __builtin_amdgcn_update_dpp(0, __float_as_int(v),
                                        DPP_WAVE_SHL1, 0xF, 0xF, true);
    return __int_as_float(r);
}

// One-time weight transpose:
// wT[(c*8 + og)*72 + oo*9 + tap] = w[((og*8+oo)*64 + c)*9 + tap]
// -> each (c, o-group) slice is 72 contiguous floats, 288B-aligned.
__global__ void wtrans_kernel(const float* __restrict__ w, float* __restrict__ wT) {
    int e = blockIdx.x * 256 + threadIdx.x;
    if (e < 64 * 8 * 8 * 9) {
        int tap = e % 9;
        int t   = e / 9;
        int oo  = t % 8;
        int t2  = t / 8;
        int og  = t2 % 8;
        int c   = t2 / 8;
        wT[e] = w[((og * 8 + oo) * 64 + c) * 9 + tap];
    }
}

__global__ __launch_bounds__(256, 4) void adder_kernel(
        const float* __restrict__ x,
        const float* __restrict__ wT,
        const float* __restrict__ alpha_p,
        float* __restrict__ out) {
    const int i    = blockIdx.x;            // output row, 0..63
    const int b    = blockIdx.y;            // batch
    const int lane = threadIdx.x & 63;      // column j
    const int wave = threadIdx.x >> 6;
    // o-group is wave-uniform; readfirstlane makes it provably scalar so the
    // weight loads below go through the scalar pipe (SGPRs, s_load_dwordx*).
    const int og = __builtin_amdgcn_readfirstlane(blockIdx.z * 4 + wave); // 0..7

    const float topm = (i > 0)  ? 1.f : 0.f;   // row halo: x=0 (still |0-w|)
    const float botm = (i < 63) ? 1.f : 0.f;
    const int   im1  = (i > 0)  ? i - 1 : i;   // clamped (masked to 0 anyway)
    const int   ip1  = (i < 63) ? i + 1 : i;

    const float* xb = x + (size_t)(b * 64) * 4096;   // channel plane stride 64*64

    float acc[8] = {0.f, 0.f, 0.f, 0.f, 0.f, 0.f, 0.f, 0.f};

    // software pipeline: preload channel 0's three rows
    float xm = topm * xb[im1 * 64 + lane];
    float x0 =        xb[i   * 64 + lane];
    float xp = botm * xb[ip1 * 64 + lane];

    for (int c = 0; c < 64; ++c) {
        // prefetch next channel's rows (clamped at the end; redundant, harmless)
        const int cn = (c < 63) ? c + 1 : c;
        const float* xc = xb + cn * 4096;
        float nm = topm * xc[im1 * 64 + lane];
        float n0 =        xc[i   * 64 + lane];
        float np = botm * xc[ip1 * 64 + lane];

        // column neighbors via DPP (zero-fill = zero halo)
        const float rl[3] = {dpp_left(xm),  dpp_left(x0),  dpp_left(xp)};
        const float rc[3] = {xm,            x0,            xp};
        const float rr[3] = {dpp_right(xm), dpp_right(x0), dpp_right(xp)};

        const float* wp = wT + (c * 8 + og) * 72;   // uniform -> s_load
        #pragma unroll
        for (int half = 0; half < 2; ++half) {      // 36 SGPRs live at a time
            float wv[36];
            #pragma unroll
            for (int t = 0; t < 36; ++t) wv[t] = wp[half * 36 + t];
            #pragma unroll
            for (int oo = 0; oo < 4; ++oo) {
                const int o4 = half * 4 + oo;
                #pragma unroll
                for (int kh = 0; kh < 3; ++kh) {
                    acc[o4] += fabsf(rl[kh] - wv[oo * 9 + kh * 3 + 0]);
                    acc[o4] += fabsf(rc[kh] - wv[oo * 9 + kh * 3 + 1]);
                    acc[o4] += fabsf(rr[kh] - wv[oo * 9 + kh * 3 + 2]);
                }
            }
        }
        xm = nm; x0 = n0; xp = np;
    }

    const float alpha = alpha_p[0];
    const int o0 = og * 8;
    #pragma unroll
    for (int oo = 0; oo < 8; ++oo) {
        const int o = o0 + oo;
        const size_t idx = (((size_t)b * 64 + o) * 64 + i) * 64 + lane;
        const float xv = x[idx];
        const float y  = xv - acc[oo];
        out[idx] = copysignf(powf(fabsf(y), alpha), y);
    }
}

extern "C" void kernel_launch(void* const* d_in, const int* in_sizes, int n_in,
                              void* d_out, int out_size, void* d_ws, size_t ws_size,
                              hipStream_t stream) {
    const float* x     = (const float*)d_in[0];
    const float* w     = (const float*)d_in[1];
    const float* alpha = (const float*)d_in[2];
    float* out = (float*)d_out;
    float* wT  = (float*)d_ws;   // 36864 floats = 147456 B

    wtrans_kernel<<<(64 * 8 * 8 * 9 + 255) / 256, 256, 0, stream>>>(w, wT);
    adder_kernel<<<dim3(64, 8, 2), 256, 0, stream>>>(x, wT, alpha, out);
}

// Round 3
// 149.970 us; speedup vs baseline: 1.6978x; 1.0198x over previous
//
#include <hip/hip_runtime.h>
#include <math.h>

// AdderNet 3x3 "convolution" + residual + sign(y)*|y|^alpha, fp32.
// B=8, C=O=64, H=W=64, K=3, pad=1.
// out[b,o,i,j] = x[b,o,i,j] - sum_{c,kh,kw} |xpad[b,c,i+kh-1,j+kw-1] - w[o,c,kh,kw]|
// then r = sign(y)*|y|^alpha.   Zero-pad taps contribute |0 - w|.
//
// R3 design: lane = column j (wave64 == W). One wave per (b, i, o-group-of-4)
// -> 8*64*16 = 8192 waves = 8/SIMD (vs 4/SIMD in R2; occupancy was 33%).
//   - x: 3 coalesced b32 loads per channel, pipelined one channel ahead;
//     j+-1 neighbors via DPP wave_shr/shl with bound_ctrl zero-fill (= halo).
//   - w: wave-uniform scalar loads (36 floats/channel), ALSO pipelined one
//     channel ahead so the per-channel s_waitcnt lgkmcnt is pre-satisfied.
//   - No LDS. abs-term = v_subrev + v_add(|mod|) = 2 VALU instr.

#define DPP_WAVE_SHL1 0x130
#define DPP_WAVE_SHR1 0x138

__device__ __forceinline__ float dpp_left(float v) {
    // lane n <- lane n-1 (x[j-1]); lane 0 <- 0 (left zero halo)
    int r = __builtin_amdgcn_update_dpp(0, __float_as_int(v),
                                        DPP_WAVE_SHR1, 0xF, 0xF, true);
    return __int_as_float(r);
}
__device__ __forceinline__ float dpp_right(float v) {
    // lane n <- lane n+1 (x[j+1]); lane 63 <- 0 (right zero halo)
    int r = __builtin_amdgcn_update_dpp(0, __float_as_int(v),
                                        DPP_WAVE_SHL1, 0xF, 0xF, true);
    return __int_as_float(r);
}

// Weight transpose: wT[(c*16 + og)*36 + oo*9 + tap] = w[((og*4+oo)*64 + c)*9 + tap]
// -> each (c, o-group-of-4) slice is 36 contiguous floats (144 B, 16B-aligned).
__global__ void wtrans_kernel(const float* __restrict__ w, float* __restrict__ wT) {
    int e = blockIdx.x * 256 + threadIdx.x;
    if (e < 64 * 16 * 36) {
        int tap = e % 9;
        int t   = e / 9;
        int oo  = t % 4;
        int t2  = t / 4;
        int og  = t2 % 16;
        int c   = t2 / 16;
        wT[e] = w[((og * 4 + oo) * 64 + c) * 9 + tap];
    }
}

__global__ __launch_bounds__(256, 8) void adder_kernel(
        const float* __restrict__ x,
        const float* __restrict__ wT,
        const float* __restrict__ alpha_p,
        float* __restrict__ out) {
    const int i    = blockIdx.x;            // output row
    const int b    = blockIdx.y;            // batch
    const int lane = threadIdx.x & 63;      // column j
    const int wave = threadIdx.x >> 6;
    // o-group (of 4) is wave-uniform; readfirstlane makes it provably scalar
    // so weight loads go through the scalar pipe (s_load -> SGPRs).
    const int og = __builtin_amdgcn_readfirstlane(blockIdx.z * 4 + wave); // 0..15

    const float topm = (i > 0)  ? 1.f : 0.f;   // row halo: x=0 (still |0-w|)
    const float botm = (i < 63) ? 1.f : 0.f;
    const int   im1  = (i > 0)  ? i - 1 : i;
    const int   ip1  = (i < 63) ? i + 1 : i;

    const float* xb = x + (size_t)(b * 64) * 4096;  // channel plane stride 4096
    const float* wb = wT + og * 36;                 // + c*576 per channel

    float acc[4] = {0.f, 0.f, 0.f, 0.f};

    // pipeline preload: channel 0's rows and weights
    float xm = topm * xb[im1 * 64 + lane];
    float x0 =        xb[i   * 64 + lane];
    float xp = botm * xb[ip1 * 64 + lane];
    float wc[36];
    #pragma unroll
    for (int t = 0; t < 36; ++t) wc[t] = wb[t];

    #pragma unroll 2
    for (int c = 0; c < 64; ++c) {
        // issue next channel's x rows and weight s_loads BEFORE compute,
        // so their waits land after this channel's VALU work
        const int cn = (c < 63) ? c + 1 : c;
        const float* xc = xb + cn * 4096;
        float nm = topm * xc[im1 * 64 + lane];
        float n0 =        xc[i   * 64 + lane];
        float np = botm * xc[ip1 * 64 + lane];
        float wn[36];
        {
            const float* wp = wb + cn * 576;
            #pragma unroll
            for (int t = 0; t < 36; ++t) wn[t] = wp[t];
        }

        const float rl[3] = {dpp_left(xm),  dpp_left(x0),  dpp_left(xp)};
        const float rc[3] = {xm,            x0,            xp};
        const float rr[3] = {dpp_right(xm), dpp_right(x0), dpp_right(xp)};

        #pragma unroll
        for (int oo = 0; oo < 4; ++oo) {
            #pragma unroll
            for (int kh = 0; kh < 3; ++kh) {
                acc[oo] += fabsf(rl[kh] - wc[oo * 9 + kh * 3 + 0]);
                acc[oo] += fabsf(rc[kh] - wc[oo * 9 + kh * 3 + 1]);
                acc[oo] += fabsf(rr[kh] - wc[oo * 9 + kh * 3 + 2]);
            }
        }

        xm = nm; x0 = n0; xp = np;
        #pragma unroll
        for (int t = 0; t < 36; ++t) wc[t] = wn[t];
    }

    const float alpha = alpha_p[0];
    #pragma unroll
    for (int oo = 0; oo < 4; ++oo) {
        const int o = og * 4 + oo;
        const size_t idx = (((size_t)b * 64 + o) * 64 + i) * 64 + lane;
        const float xv = x[idx];
        const float y  = xv - acc[oo];
        out[idx] = copysignf(powf(fabsf(y), alpha), y);
    }
}

extern "C" void kernel_launch(void* const* d_in, const int* in_sizes, int n_in,
                              void* d_out, int out_size, void* d_ws, size_t ws_size,
                              hipStream_t stream) {
    const float* x     = (const float*)d_in[0];
    const float* w     = (const float*)d_in[1];
    const float* alpha = (const float*)d_in[2];
    float* out = (float*)d_out;
    float* wT  = (float*)d_ws;   // 64*16*36 floats = 147456 B

    wtrans_kernel<<<(64 * 16 * 36 + 255) / 256, 256, 0, stream>>>(w, wT);
    adder_kernel<<<dim3(64, 8, 4), 256, 0, stream>>>(x, wT, alpha, out);
}